// Round 10
// baseline (288.504 us; speedup 1.0000x reference)
//
#include <hip/hip_runtime.h>
#include <stdint.h>

#define NPIX 9216   // 96*96
#define NIMG 32
#define SSTRIP 1024 // kscore strip: 9 per image

// ---------- JAX threefry2x32 (20 rounds), bit-exact (verified rounds 1-9) ----------
__device__ __forceinline__ uint32_t rotl32(uint32_t x, int d){ return (x<<d)|(x>>(32-d)); }

__device__ __forceinline__ void threefry(uint32_t k0, uint32_t k1, uint32_t x0, uint32_t x1,
                                         uint32_t &o0, uint32_t &o1){
  uint32_t ks2 = k0 ^ k1 ^ 0x1BD11BDAu;
  x0 += k0; x1 += k1;
  x0+=x1; x1=rotl32(x1,13); x1^=x0;
  x0+=x1; x1=rotl32(x1,15); x1^=x0;
  x0+=x1; x1=rotl32(x1,26); x1^=x0;
  x0+=x1; x1=rotl32(x1,6);  x1^=x0;
  x0+=k1; x1+=ks2+1u;
  x0+=x1; x1=rotl32(x1,17); x1^=x0;
  x0+=x1; x1=rotl32(x1,29); x1^=x0;
  x0+=x1; x1=rotl32(x1,16); x1^=x0;
  x0+=x1; x1=rotl32(x1,24); x1^=x0;
  x0+=ks2; x1+=k0+2u;
  x0+=x1; x1=rotl32(x1,13); x1^=x0;
  x0+=x1; x1=rotl32(x1,15); x1^=x0;
  x0+=x1; x1=rotl32(x1,26); x1^=x0;
  x0+=x1; x1=rotl32(x1,6);  x1^=x0;
  x0+=k0; x1+=k1+3u;
  x0+=x1; x1=rotl32(x1,17); x1^=x0;
  x0+=x1; x1=rotl32(x1,29); x1^=x0;
  x0+=x1; x1=rotl32(x1,16); x1^=x0;
  x0+=x1; x1=rotl32(x1,24); x1^=x0;
  x0+=k1; x1+=ks2+4u;
  x0+=x1; x1=rotl32(x1,13); x1^=x0;
  x0+=x1; x1=rotl32(x1,15); x1^=x0;
  x0+=x1; x1=rotl32(x1,26); x1^=x0;
  x0+=x1; x1=rotl32(x1,6);  x1^=x0;
  x0+=ks2; x1+=k0+5u;
  o0=x0; o1=x1;
}

__device__ __forceinline__ float clip01_div255(float x){
  return fminf(fmaxf(x/255.0f, 0.0f), 1.0f);
}

// ---------- K0: partial channel max, 6 blocks/image (reads image exactly once) -----
__global__ __launch_bounds__(256) void kmax(const float* __restrict__ in,
                                            float* __restrict__ maxpart){
  int img  = blockIdx.x / 6;
  int part = blockIdx.x % 6;
  int tid  = threadIdx.x;
  const float* base = in + (size_t)img*NPIX*3 + (size_t)part*1536*3;
  float m0=0.f, m1=0.f, m2=0.f;
#pragma unroll
  for(int k=0;k<18;k++){
    int g = k*256 + tid;
    float v = clip01_div255(base[g]);
    int c = g % 3;
    m0 = (c==0) ? fmaxf(m0,v) : m0;
    m1 = (c==1) ? fmaxf(m1,v) : m1;
    m2 = (c==2) ? fmaxf(m2,v) : m2;
  }
  for(int off=32; off>0; off>>=1){
    m0 = fmaxf(m0, __shfl_down(m0,off));
    m1 = fmaxf(m1, __shfl_down(m1,off));
    m2 = fmaxf(m2, __shfl_down(m2,off));
  }
  __shared__ float r[3][4];
  int lane = tid & 63, wv = tid >> 6;
  if(lane==0){ r[0][wv]=m0; r[1][wv]=m1; r[2][wv]=m2; }
  __syncthreads();
  if(tid==0){
    maxpart[blockIdx.x*3+0]=fmaxf(fmaxf(r[0][0],r[0][1]),fmaxf(r[0][2],r[0][3]));
    maxpart[blockIdx.x*3+1]=fmaxf(fmaxf(r[1][0],r[1][1]),fmaxf(r[1][2],r[1][3]));
    maxpart[blockIdx.x*3+2]=fmaxf(fmaxf(r[2][0],r[2][1]),fmaxf(r[2][2],r[2][3]));
  }
}

// ---------- K1: 576 blocks = img x cls x 9 strips of 1024 px.
// Registers-only staging (thread t owns 4 whole pixels), valid-only histogram,
// exact local top-50 keys. No fences, no LDS pixel buffer. ----------
__global__ __launch_bounds__(256) void kscore(const float* __restrict__ in,
                                              const float* __restrict__ maxpart,
                                              unsigned long long* __restrict__ key50g){
#pragma clang fp contract(off)
  int b   = blockIdx.x;                 // img*18 + cls*9 + sub
  int img = b / 18;
  int rr  = b % 18;
  int cls = rr / 9, sub = rr % 9;
  int tid = threadIdx.x;

  __shared__ uint64_t cand[1024];
  __shared__ int hist[129];
  __shared__ int ncand, bbin;

  if(tid<129) hist[tid]=0;
  if(tid==0)  ncand=0;

  const float* p = in + (size_t)img*NPIX*3;

  // stage 4 whole pixels into registers: 3 consecutive float4 per thread
  const float4* sp4 = (const float4*)(p + (size_t)sub*SSTRIP*3);
  float4 v0 = sp4[3*tid+0];
  float4 v1 = sp4[3*tid+1];
  float4 v2 = sp4[3*tid+2];

  // fold 6 partial maxes (uniform -> scalar loads; fmax exactly associative)
  float c0=0.f,c1=0.f,c2=0.f;
#pragma unroll
  for(int s=0;s<6;s++){
    c0=fmaxf(c0, maxpart[(img*6+s)*3+0]);
    c1=fmaxf(c1, maxpart[(img*6+s)*3+1]);
    c2=fmaxf(c2, maxpart[(img*6+s)*3+2]);
  }

  // partitionable threefry (bit-exact); overlaps the in-flight pixel loads
  uint32_t ik0, ik1; threefry(0u, 42u, 0u, (uint32_t)img, ik0, ik1);
  uint32_t s0, s1;   threefry(ik0, ik1, 0u, (uint32_t)cls, s0, s1);
  int gibase = sub*SSTRIP + 4*tid;
  uint32_t rngv[4];
#pragma unroll
  for(int k=0;k<4;k++){
    uint32_t r1,r2; threefry(s0, s1, 0u, (uint32_t)(gibase+k), r1, r2);
    rngv[k] = r1 ^ r2;
  }
  __syncthreads();                      // hist zero visible before atomics

  // score own 4 pixels (math bit-identical to rounds 1-9); valid-only hist adds
  float px0[4]={v0.x, v0.w, v1.z, v2.y};
  float px1[4]={v0.y, v1.x, v1.w, v2.z};
  float px2[4]={v0.z, v1.y, v2.x, v2.w};
  uint32_t vv[4];
#pragma unroll
  for(int k=0;k<4;k++){
    float a  = clip01_div255(px0[k])/c0;
    float bb = clip01_div255(px1[k])/c1;
    float c  = clip01_div255(px2[k])/c2;
    bool fg = (a>0.f && a<0.6f) || (bb>0.f && bb<0.6f) || (c>0.f && c<0.6f);
    bool valid = (cls==0) ? fg : !fg;
    vv[k] = valid ? (rngv[k] >> 9) + 1u : 0u;   // monotone in uniform; 0 = invalid(-1.0)
    if(vv[k]) atomicAdd(&hist[vv[k]>>16], 1);
  }
  __syncthreads();
  if(tid==0){
    int acc=0, bx=128;
    for(; bx>=1; bx--){ acc += hist[bx]; if(acc>=50) break; }
    bbin = (acc>=50) ? bx : 0;          // <50 valid in strip -> include everything
  }
  __syncthreads();
  int bb = bbin;
#pragma unroll
  for(int k=0;k<4;k++){
    if((int)(vv[k]>>16) >= bb){
      int pos = atomicAdd(&ncand,1);
      cand[pos] = ((uint64_t)vv[k] << 14) | (uint64_t)(16383 - (gibase+k));  // higher = earlier
    }
  }
  __syncthreads();
  int m = ncand;
  for(int c=tid;c<m;c+=256){
    uint64_t k = cand[c];
    int r = 0, j = 0;
    while(j < m){                        // chunked early-exit: exact for r<50
      int je = j+64 < m ? j+64 : m;
      for(; j<je; j++) r += (cand[j] > k);
      if(r >= 50) break;
    }
    if(r < 50) key50g[(size_t)b*50 + r] = k;  // rank r -> descending sorted list
  }
}

// ---------- K2 (32 blocks): merge 18 strip lists -> top-50/class -> stats -> pack ---
__global__ __launch_bounds__(256) void kmerge(const float* __restrict__ in,
                                              const unsigned long long* __restrict__ key50g,
                                              float* __restrict__ ts2g,      // [32][600]
                                              float* __restrict__ meanstd){  // [32][10]
#pragma clang fp contract(off)
  int img = blockIdx.x;
  int tid = threadIdx.x;
  __shared__ uint64_t kk[900];           // 18 lists x 50 (cls0: 0..449, cls1: 450..899)
  __shared__ int      tIdx[100];
  __shared__ float    feat[100][5];
  __shared__ float    mv[5], sv[5];

  const uint64_t* kg = (const uint64_t*)key50g + (size_t)img*900;
  for(int c=tid;c<900;c+=256) kk[c] = kg[c];
  __syncthreads();

  // global rank within class via binary search on 9 descending 50-lists (keys unique)
  for(int c=tid;c<900;c+=256){
    uint64_t k = kk[c];
    int cl = (c >= 450);
    int base = cl*450;
    int r = 0;
#pragma unroll
    for(int s=0;s<9;s++){
      const uint64_t* L = &kk[base + s*50];
      int lo=0, hi=50;
      while(lo<hi){ int mid=(lo+hi)>>1; if(L[mid] > k) lo=mid+1; else hi=mid; }
      r += lo;
    }
    if(r < 50) tIdx[cl*50+r] = 16383 - (int)(k & 16383u);
  }
  __syncthreads();

  // train features + stats (math bit-identical to rounds 1-9)
  if(tid<100){
    int pp = tIdx[tid];
    int i=pp/96, j=pp-i*96;
    const float* px = in + ((size_t)img*NPIX + pp)*3;
    for(int c=0;c<3;c++){
      float ip=clip01_div255(px[c]);
      feat[tid][c]=ip/255.0f;
    }
    feat[tid][3]=((float)i/96.0f)*100.0f;
    feat[tid][4]=((float)j/96.0f)*100.0f;
  }
  __syncthreads();
  if(tid<5){
    float s=0.f;
    for(int r=0;r<100;r++) s=s+feat[r][tid];
    float mu=s/100.0f; mv[tid]=mu;
    float v=0.f;
    for(int r=0;r<100;r++){ float d=feat[r][tid]-mu; float q=d*d; v=v+q; }
    sv[tid]=sqrtf(v/100.0f);
  }
  __syncthreads();
  // pair-packed layout: pair p holds rows 2p (f0..4), 2p+1 (f5..9), pad 2
  if(tid<100){
    float r0=(feat[tid][0]-mv[0])/sv[0];
    float r1=(feat[tid][1]-mv[1])/sv[1];
    float r2=(feat[tid][2]-mv[2])/sv[2];
    float r3=(feat[tid][3]-mv[3])/sv[3];
    float r4=(feat[tid][4]-mv[4])/sv[4];
    float* dst = ts2g + img*600 + (tid>>1)*12 + (tid&1)*5;
    dst[0]=r0; dst[1]=r1; dst[2]=r2; dst[3]=r3; dst[4]=r4;
  }
  if(tid<5)       meanstd[img*10+tid]=mv[tid];
  else if(tid<10) meanstd[img*10+tid]=sv[tid-5];
}

// ---------- K3: 1152 blocks: 5-NN with 4 independent select chains + exact merges --
__global__ __launch_bounds__(256) void kknn(const float* __restrict__ in,
                                            const float* __restrict__ ts2g,
                                            const float* __restrict__ meanstd,
                                            float* __restrict__ out){
#pragma clang fp contract(off)
  int b     = blockIdx.x;
  int img   = b / 36;
  int chunk = b % 36;
  int tid   = threadIdx.x;

  __shared__ float    mv[5], sv[5];
  __shared__ __attribute__((aligned(16))) float ts2[600];  // pair-packed train rows
  __shared__ __attribute__((aligned(16))) float pix[768];

  if(tid<150) ((float4*)ts2)[tid] = ((const float4*)(ts2g + img*600))[tid];
  if(tid>=192 && tid<197) mv[tid-192]=meanstd[img*10+(tid-192)];
  if(tid>=224 && tid<229) sv[tid-224]=meanstd[img*10+5+(tid-224)];
  {
    const float4* cb4 = (const float4*)(in + ((size_t)img*NPIX + (size_t)chunk*256)*3);
    if(tid<192) ((float4*)pix)[tid] = cb4[tid];
  }
  __syncthreads();

  // test feature for own pixel (bit-identical math)
  int p = chunk*256+tid;
  int i=p/96, j=p-i*96;
  float ip0=clip01_div255(pix[tid*3+0]);
  float ip1=clip01_div255(pix[tid*3+1]);
  float ip2=clip01_div255(pix[tid*3+2]);
  float t0,t1,t2,t3,t4;
  {
    float f0=ip0/255.0f, f1=ip1/255.0f, f2=ip2/255.0f;
    float f3=((float)i/96.0f)*100.0f, f4=((float)j/96.0f)*100.0f;
    t0=(f0-mv[0])/sv[0]; t1=(f1-mv[1])/sv[1]; t2=(f2-mv[2])/sv[2];
    t3=(f3-mv[3])/sv[3]; t4=(f4-mv[4])/sv[4];
  }

  // fg rows 0..49: two independent top-2 chains (even row -> E, odd row -> O);
  // per-row d^2 op order identical to rounds 6-9; selection in d^2 (sqrt monotone).
  float aE0=1e30f,aE1=1e30f, aO0=1e30f,aO1=1e30f;
#pragma unroll 5
  for(int pr=0;pr<25;pr++){
    const float* tp = &ts2[pr*12];
    float4 qa = *(const float4*)(tp);    // r0: f0..f3
    float4 qb = *(const float4*)(tp+4);  // r0f4 | r1: f0..f2
    float2 qc = *(const float2*)(tp+8);  // r1: f3,f4
    {
      float s;
      { float d=t0-qa.x; s=d*d; }
      { float d=t1-qa.y; float w=d*d; s=s+w; }
      { float d=t2-qa.z; float w=d*d; s=s+w; }
      { float d=t3-qa.w; float w=d*d; s=s+w; }
      { float d=t4-qb.x; float w=d*d; s=s+w; }
      bool l0=s<aE0,l1=s<aE1;
      aE1 = l1 ? (l0?aE0:s) : aE1;
      aE0 = l0 ? s : aE0;
    }
    {
      float s;
      { float d=t0-qb.y; s=d*d; }
      { float d=t1-qb.z; float w=d*d; s=s+w; }
      { float d=t2-qb.w; float w=d*d; s=s+w; }
      { float d=t3-qc.x; float w=d*d; s=s+w; }
      { float d=t4-qc.y; float w=d*d; s=s+w; }
      bool l0=s<aO0,l1=s<aO1;
      aO1 = l1 ? (l0?aO0:s) : aO1;
      aO0 = l0 ? s : aO0;
    }
  }
  // exact 2nd-smallest of union of two sorted pairs (bitonic split)
  float a1 = fmaxf(fminf(aE0,aO1), fminf(aE1,aO0));

  // bg rows 50..99: two independent top-4 chains
  float bP0=1e30f,bP1=1e30f,bP2=1e30f,bP3=1e30f;
  float bQ0=1e30f,bQ1=1e30f,bQ2=1e30f,bQ3=1e30f;
#pragma unroll 5
  for(int pr=25;pr<50;pr++){
    const float* tp = &ts2[pr*12];
    float4 qa = *(const float4*)(tp);
    float4 qb = *(const float4*)(tp+4);
    float2 qc = *(const float2*)(tp+8);
    {
      float s;
      { float d=t0-qa.x; s=d*d; }
      { float d=t1-qa.y; float w=d*d; s=s+w; }
      { float d=t2-qa.z; float w=d*d; s=s+w; }
      { float d=t3-qa.w; float w=d*d; s=s+w; }
      { float d=t4-qb.x; float w=d*d; s=s+w; }
      bool l0=s<bP0,l1=s<bP1,l2=s<bP2,l3=s<bP3;
      bP3 = l3 ? (l2?bP2:s) : bP3;
      bP2 = l2 ? (l1?bP1:s) : bP2;
      bP1 = l1 ? (l0?bP0:s) : bP1;
      bP0 = l0 ? s : bP0;
    }
    {
      float s;
      { float d=t0-qb.y; s=d*d; }
      { float d=t1-qb.z; float w=d*d; s=s+w; }
      { float d=t2-qb.w; float w=d*d; s=s+w; }
      { float d=t3-qc.x; float w=d*d; s=s+w; }
      { float d=t4-qc.y; float w=d*d; s=s+w; }
      bool l0=s<bQ0,l1=s<bQ1,l2=s<bQ2,l3=s<bQ3;
      bQ3 = l3 ? (l2?bQ2:s) : bQ3;
      bQ2 = l2 ? (l1?bQ1:s) : bQ2;
      bQ1 = l1 ? (l0?bQ0:s) : bQ1;
      bQ0 = l0 ? s : bQ0;
    }
  }
  // exact 4th-smallest of union of two sorted quads (bitonic lower-half merge)
  float l0=fminf(bP0,bQ3), l1=fminf(bP1,bQ2), l2=fminf(bP2,bQ1), l3=fminf(bP3,bQ0);
  float b3 = fmaxf(fmaxf(l0,l1), fmaxf(l2,l3));

  // seg <=> 2nd-smallest fg sqrt-dist <= 4th-smallest bg sqrt-dist (fg wins ties)
  bool seg = sqrtf(a1) <= sqrtf(b3);
  __syncthreads();                       // pix reuse fence
  pix[tid*3+0]=seg?ip0:0.f;
  pix[tid*3+1]=seg?ip1:0.f;
  pix[tid*3+2]=seg?ip2:0.f;
  __syncthreads();
  float4* ob4 = (float4*)(out + ((size_t)img*NPIX + (size_t)chunk*256)*3);
  if(tid<192) ob4[tid] = ((float4*)pix)[tid];
}

extern "C" void kernel_launch(void* const* d_in, const int* in_sizes, int n_in,
                              void* d_out, int out_size, void* d_ws, size_t ws_size,
                              hipStream_t stream) {
  const float* in = (const float*)d_in[0];
  float* out = (float*)d_out;
  float* maxpart = (float*)d_ws;                                          // 2304 B
  unsigned long long* key50g = (unsigned long long*)((char*)d_ws + 2304); // 576*50*8 = 230400 B
  float* ts2g    = (float*)((char*)d_ws + 232704);                        // 76800 B
  float* meanstd = (float*)((char*)d_ws + 309504);                        // 1280 B

  kmax  <<<192,  256, 0, stream>>>(in, maxpart);
  kscore<<<576,  256, 0, stream>>>(in, maxpart, key50g);
  kmerge<<<32,   256, 0, stream>>>(in, key50g, ts2g, meanstd);
  kknn  <<<1152, 256, 0, stream>>>(in, ts2g, meanstd, out);
}

// Round 11
// 105.434 us; speedup vs baseline: 2.7363x; 2.7363x over previous
//
#include <hip/hip_runtime.h>
#include <stdint.h>

#define NPIX 9216   // 96*96
#define NIMG 32
#define STRIP 1152  // NPIX / 8 strips

// ---------- JAX threefry2x32 (20 rounds), bit-exact (verified rounds 1-10) ----------
__device__ __forceinline__ uint32_t rotl32(uint32_t x, int d){ return (x<<d)|(x>>(32-d)); }

__device__ __forceinline__ void threefry(uint32_t k0, uint32_t k1, uint32_t x0, uint32_t x1,
                                         uint32_t &o0, uint32_t &o1){
  uint32_t ks2 = k0 ^ k1 ^ 0x1BD11BDAu;
  x0 += k0; x1 += k1;
  x0+=x1; x1=rotl32(x1,13); x1^=x0;
  x0+=x1; x1=rotl32(x1,15); x1^=x0;
  x0+=x1; x1=rotl32(x1,26); x1^=x0;
  x0+=x1; x1=rotl32(x1,6);  x1^=x0;
  x0+=k1; x1+=ks2+1u;
  x0+=x1; x1=rotl32(x1,17); x1^=x0;
  x0+=x1; x1=rotl32(x1,29); x1^=x0;
  x0+=x1; x1=rotl32(x1,16); x1^=x0;
  x0+=x1; x1=rotl32(x1,24); x1^=x0;
  x0+=ks2; x1+=k0+2u;
  x0+=x1; x1=rotl32(x1,13); x1^=x0;
  x0+=x1; x1=rotl32(x1,15); x1^=x0;
  x0+=x1; x1=rotl32(x1,26); x1^=x0;
  x0+=x1; x1=rotl32(x1,6);  x1^=x0;
  x0+=k0; x1+=k1+3u;
  x0+=x1; x1=rotl32(x1,17); x1^=x0;
  x0+=x1; x1=rotl32(x1,29); x1^=x0;
  x0+=x1; x1=rotl32(x1,16); x1^=x0;
  x0+=x1; x1=rotl32(x1,24); x1^=x0;
  x0+=k1; x1+=ks2+4u;
  x0+=x1; x1=rotl32(x1,13); x1^=x0;
  x0+=x1; x1=rotl32(x1,15); x1^=x0;
  x0+=x1; x1=rotl32(x1,26); x1^=x0;
  x0+=x1; x1=rotl32(x1,6);  x1^=x0;
  x0+=ks2; x1+=k0+5u;
  o0=x0; o1=x1;
}

__device__ __forceinline__ float clip01_div255(float x){
  return fminf(fmaxf(x/255.0f, 0.0f), 1.0f);
}

// ---------- K0: partial channel max, 6 blocks/image (reads image exactly once) -----
__global__ __launch_bounds__(256) void kmax(const float* __restrict__ in,
                                            float* __restrict__ maxpart){
  int img  = blockIdx.x / 6;
  int part = blockIdx.x % 6;
  int tid  = threadIdx.x;
  const float* base = in + (size_t)img*NPIX*3 + (size_t)part*1536*3;
  float m0=0.f, m1=0.f, m2=0.f;
#pragma unroll
  for(int k=0;k<18;k++){
    int g = k*256 + tid;
    float v = clip01_div255(base[g]);
    int c = g % 3;
    m0 = (c==0) ? fmaxf(m0,v) : m0;
    m1 = (c==1) ? fmaxf(m1,v) : m1;
    m2 = (c==2) ? fmaxf(m2,v) : m2;
  }
  for(int off=32; off>0; off>>=1){
    m0 = fmaxf(m0, __shfl_down(m0,off));
    m1 = fmaxf(m1, __shfl_down(m1,off));
    m2 = fmaxf(m2, __shfl_down(m2,off));
  }
  __shared__ float r[3][4];
  int lane = tid & 63, wv = tid >> 6;
  if(lane==0){ r[0][wv]=m0; r[1][wv]=m1; r[2][wv]=m2; }
  __syncthreads();
  if(tid==0){
    maxpart[blockIdx.x*3+0]=fmaxf(fmaxf(r[0][0],r[0][1]),fmaxf(r[0][2],r[0][3]));
    maxpart[blockIdx.x*3+1]=fmaxf(fmaxf(r[1][0],r[1][1]),fmaxf(r[1][2],r[1][3]));
    maxpart[blockIdx.x*3+2]=fmaxf(fmaxf(r[2][0],r[2][1]),fmaxf(r[2][2],r[2][3]));
  }
}

// ---------- K1: 512 blocks = img x cls x 8 strips (R7-verified structure).
// LDS staging, full histogram, exact local top-50; bbin via single-wave shfl scan. --
__global__ __launch_bounds__(256) void kscore(const float* __restrict__ in,
                                              const float* __restrict__ maxpart,
                                              unsigned long long* __restrict__ key50g){
#pragma clang fp contract(off)
  int b   = blockIdx.x;                 // img*16 + cls*8 + sub
  int img = b >> 4, cls = (b >> 3) & 1, sub = b & 7;
  int tid = threadIdx.x;

  __shared__ __attribute__((aligned(16))) float pixL[3456];  // strip pixels
  __shared__ uint32_t vvL[STRIP];
  __shared__ uint64_t cand[STRIP];
  __shared__ int hist[129];
  __shared__ int ncand, bbin;

  if(tid<129) hist[tid]=0;
  if(tid==0)  ncand=0;

  const float* p = in + (size_t)img*NPIX*3;

  // stage own strip (864 float4, coalesced)
  const float4* sp4 = (const float4*)(p + (size_t)sub*STRIP*3);
  float4* pixL4 = (float4*)pixL;
  for(int k=0;k<4;k++){ int i4=k*256+tid; if(i4<864) pixL4[i4]=sp4[i4]; }

  // fold 6 partial maxes (uniform -> scalar loads; fmax exactly associative)
  float c0=0.f,c1=0.f,c2=0.f;
#pragma unroll
  for(int s=0;s<6;s++){
    c0=fmaxf(c0, maxpart[(img*6+s)*3+0]);
    c1=fmaxf(c1, maxpart[(img*6+s)*3+1]);
    c2=fmaxf(c2, maxpart[(img*6+s)*3+2]);
  }

  // partitionable threefry keys (bit-exact)
  uint32_t ik0, ik1; threefry(0u, 42u, 0u, (uint32_t)img, ik0, ik1);
  uint32_t s0, s1;   threefry(ik0, ik1, 0u, (uint32_t)cls, s0, s1);
  __syncthreads();

  // score strip + histogram (math bit-identical to rounds 6-9)
  for(int r=0;r<5;r++){
    int pi = tid + r*256;
    if(pi<STRIP){
      float a  = clip01_div255(pixL[pi*3+0])/c0;
      float bb = clip01_div255(pixL[pi*3+1])/c1;
      float c  = clip01_div255(pixL[pi*3+2])/c2;
      bool fg = (a>0.f && a<0.6f) || (bb>0.f && bb<0.6f) || (c>0.f && c<0.6f);
      bool valid = (cls==0) ? fg : !fg;
      uint32_t gi = (uint32_t)(sub*STRIP + pi);
      uint32_t r1,r2; threefry(s0, s1, 0u, gi, r1, r2);
      uint32_t vv = valid ? ((r1 ^ r2) >> 9) + 1u : 0u;  // monotone in uniform; 0 = invalid(-1.0)
      vvL[pi] = vv;
      atomicAdd(&hist[vv>>16], 1);
    }
  }
  __syncthreads();

  // bbin = largest bin with suffix-count >= 50 (wave-parallel, replaces tid0 scan;
  // identical semantics to the R7 serial loop). Lane l owns bins 2l, 2l+1.
  if(tid < 64){
    int h0 = hist[2*tid];
    int h1 = hist[2*tid+1];
    int h128 = hist[128];
    int S = h0 + h1;                    // suffix over lane-pairs
    for(int off=1; off<64; off<<=1){
      int o = __shfl_down(S, off);
      if(tid + off < 64) S += o;
    }
    int ss0 = S + h128;                 // suffix at bin 2l
    int ss1 = S - h0 + h128;            // suffix at bin 2l+1
    int cd = -1;
    if(ss0 >= 50) cd = 2*tid;
    if(ss1 >= 50) cd = 2*tid+1;
    if(tid==63 && h128 >= 50) cd = 128;
    for(int off=32; off>0; off>>=1){    // wave max
      int o = __shfl_down(cd, off);
      cd = o > cd ? o : cd;
    }
    if(tid==0) bbin = cd;               // ss(0)=1152>=50 -> cd>=0 guaranteed
  }
  __syncthreads();

  int bb = bbin;
  for(int r=0;r<5;r++){
    int pi = tid + r*256;
    if(pi<STRIP){
      uint32_t vv = vvL[pi];
      if((int)(vv>>16) >= bb){
        int pos = atomicAdd(&ncand,1);
        cand[pos] = ((uint64_t)vv << 14) | (uint64_t)(16383 - (sub*STRIP + pi));  // higher = earlier
      }
    }
  }
  __syncthreads();
  int m = ncand;
  for(int c=tid;c<m;c+=256){
    uint64_t k = cand[c];
    int r = 0, j = 0;
    while(j < m){                        // chunked early-exit: exact for r<50
      int je = j+64 < m ? j+64 : m;
      for(; j<je; j++) r += (cand[j] > k);
      if(r >= 50) break;
    }
    if(r < 50) key50g[(size_t)b*50 + r] = k;  // rank r -> descending sorted list
  }
}

// ---------- K2 (32 blocks): merge 16 strip lists -> top-50/class -> stats -> pack ---
__global__ __launch_bounds__(256) void kmerge(const float* __restrict__ in,
                                              const unsigned long long* __restrict__ key50g,
                                              float* __restrict__ ts2g,      // [32][600]
                                              float* __restrict__ meanstd){  // [32][10]
#pragma clang fp contract(off)
  int img = blockIdx.x;
  int tid = threadIdx.x;
  __shared__ uint64_t kk[800];
  __shared__ int      tIdx[100];
  __shared__ float    feat[100][5];
  __shared__ float    mv[5], sv[5];

  const uint64_t* kg = (const uint64_t*)key50g + (size_t)img*800;
  for(int c=tid;c<800;c+=256) kk[c] = kg[c];
  __syncthreads();

  // global rank within class via binary search on 8 descending 50-lists (keys unique)
  for(int c=tid;c<800;c+=256){
    uint64_t k = kk[c];
    int cl = (c >= 400);
    int base = cl*400;
    int r = 0;
#pragma unroll
    for(int s=0;s<8;s++){
      const uint64_t* L = &kk[base + s*50];
      int lo=0, hi=50;
      while(lo<hi){ int mid=(lo+hi)>>1; if(L[mid] > k) lo=mid+1; else hi=mid; }
      r += lo;
    }
    if(r < 50) tIdx[cl*50+r] = 16383 - (int)(k & 16383u);
  }
  __syncthreads();

  // train features + stats (math bit-identical to rounds 1-10)
  if(tid<100){
    int pp = tIdx[tid];
    int i=pp/96, j=pp-i*96;
    const float* px = in + ((size_t)img*NPIX + pp)*3;
    for(int c=0;c<3;c++){
      float ip=clip01_div255(px[c]);
      feat[tid][c]=ip/255.0f;
    }
    feat[tid][3]=((float)i/96.0f)*100.0f;
    feat[tid][4]=((float)j/96.0f)*100.0f;
  }
  __syncthreads();
  if(tid<5){
    float s=0.f;
    for(int r=0;r<100;r++) s=s+feat[r][tid];
    float mu=s/100.0f; mv[tid]=mu;
    float v=0.f;
    for(int r=0;r<100;r++){ float d=feat[r][tid]-mu; float q=d*d; v=v+q; }
    sv[tid]=sqrtf(v/100.0f);
  }
  __syncthreads();
  // pair-packed layout: pair p holds rows 2p (f0..4), 2p+1 (f5..9), pad 2
  if(tid<100){
    float r0=(feat[tid][0]-mv[0])/sv[0];
    float r1=(feat[tid][1]-mv[1])/sv[1];
    float r2=(feat[tid][2]-mv[2])/sv[2];
    float r3=(feat[tid][3]-mv[3])/sv[3];
    float r4=(feat[tid][4]-mv[4])/sv[4];
    float* dst = ts2g + img*600 + (tid>>1)*12 + (tid&1)*5;
    dst[0]=r0; dst[1]=r1; dst[2]=r2; dst[3]=r3; dst[4]=r4;
  }
  if(tid<5)       meanstd[img*10+tid]=mv[tid];
  else if(tid<10) meanstd[img*10+tid]=sv[tid-5];
}

// ---------- K3: 1152 blocks: 5-NN, 4 independent select chains + exact bitonic merges
__global__ __launch_bounds__(256) void kknn(const float* __restrict__ in,
                                            const float* __restrict__ ts2g,
                                            const float* __restrict__ meanstd,
                                            float* __restrict__ out){
#pragma clang fp contract(off)
  int b     = blockIdx.x;
  int img   = b / 36;
  int chunk = b % 36;
  int tid   = threadIdx.x;

  __shared__ float    mv[5], sv[5];
  __shared__ __attribute__((aligned(16))) float ts2[600];  // pair-packed train rows
  __shared__ __attribute__((aligned(16))) float pix[768];

  if(tid<150) ((float4*)ts2)[tid] = ((const float4*)(ts2g + img*600))[tid];
  if(tid>=192 && tid<197) mv[tid-192]=meanstd[img*10+(tid-192)];
  if(tid>=224 && tid<229) sv[tid-224]=meanstd[img*10+5+(tid-224)];
  {
    const float4* cb4 = (const float4*)(in + ((size_t)img*NPIX + (size_t)chunk*256)*3);
    if(tid<192) ((float4*)pix)[tid] = cb4[tid];
  }
  __syncthreads();

  // test feature for own pixel (bit-identical math)
  int p = chunk*256+tid;
  int i=p/96, j=p-i*96;
  float ip0=clip01_div255(pix[tid*3+0]);
  float ip1=clip01_div255(pix[tid*3+1]);
  float ip2=clip01_div255(pix[tid*3+2]);
  float t0,t1,t2,t3,t4;
  {
    float f0=ip0/255.0f, f1=ip1/255.0f, f2=ip2/255.0f;
    float f3=((float)i/96.0f)*100.0f, f4=((float)j/96.0f)*100.0f;
    t0=(f0-mv[0])/sv[0]; t1=(f1-mv[1])/sv[1]; t2=(f2-mv[2])/sv[2];
    t3=(f3-mv[3])/sv[3]; t4=(f4-mv[4])/sv[4];
  }

  // fg rows 0..49: two independent top-2 chains (even row E, odd row O);
  // per-row d^2 op order identical to rounds 6-10; selection in d^2 (sqrt monotone).
  float aE0=1e30f,aE1=1e30f, aO0=1e30f,aO1=1e30f;
#pragma unroll 5
  for(int pr=0;pr<25;pr++){
    const float* tp = &ts2[pr*12];
    float4 qa = *(const float4*)(tp);    // r0: f0..f3
    float4 qb = *(const float4*)(tp+4);  // r0f4 | r1: f0..f2
    float2 qc = *(const float2*)(tp+8);  // r1: f3,f4
    {
      float s;
      { float d=t0-qa.x; s=d*d; }
      { float d=t1-qa.y; float w=d*d; s=s+w; }
      { float d=t2-qa.z; float w=d*d; s=s+w; }
      { float d=t3-qa.w; float w=d*d; s=s+w; }
      { float d=t4-qb.x; float w=d*d; s=s+w; }
      bool l0=s<aE0,l1=s<aE1;
      aE1 = l1 ? (l0?aE0:s) : aE1;
      aE0 = l0 ? s : aE0;
    }
    {
      float s;
      { float d=t0-qb.y; s=d*d; }
      { float d=t1-qb.z; float w=d*d; s=s+w; }
      { float d=t2-qb.w; float w=d*d; s=s+w; }
      { float d=t3-qc.x; float w=d*d; s=s+w; }
      { float d=t4-qc.y; float w=d*d; s=s+w; }
      bool l0=s<aO0,l1=s<aO1;
      aO1 = l1 ? (l0?aO0:s) : aO1;
      aO0 = l0 ? s : aO0;
    }
  }
  // exact 2nd-smallest of union of two sorted pairs (bitonic split)
  float a1 = fmaxf(fminf(aE0,aO1), fminf(aE1,aO0));

  // bg rows 50..99: two independent top-4 chains
  float bP0=1e30f,bP1=1e30f,bP2=1e30f,bP3=1e30f;
  float bQ0=1e30f,bQ1=1e30f,bQ2=1e30f,bQ3=1e30f;
#pragma unroll 5
  for(int pr=25;pr<50;pr++){
    const float* tp = &ts2[pr*12];
    float4 qa = *(const float4*)(tp);
    float4 qb = *(const float4*)(tp+4);
    float2 qc = *(const float2*)(tp+8);
    {
      float s;
      { float d=t0-qa.x; s=d*d; }
      { float d=t1-qa.y; float w=d*d; s=s+w; }
      { float d=t2-qa.z; float w=d*d; s=s+w; }
      { float d=t3-qa.w; float w=d*d; s=s+w; }
      { float d=t4-qb.x; float w=d*d; s=s+w; }
      bool l0=s<bP0,l1=s<bP1,l2=s<bP2,l3=s<bP3;
      bP3 = l3 ? (l2?bP2:s) : bP3;
      bP2 = l2 ? (l1?bP1:s) : bP2;
      bP1 = l1 ? (l0?bP0:s) : bP1;
      bP0 = l0 ? s : bP0;
    }
    {
      float s;
      { float d=t0-qb.y; s=d*d; }
      { float d=t1-qb.z; float w=d*d; s=s+w; }
      { float d=t2-qb.w; float w=d*d; s=s+w; }
      { float d=t3-qc.x; float w=d*d; s=s+w; }
      { float d=t4-qc.y; float w=d*d; s=s+w; }
      bool l0=s<bQ0,l1=s<bQ1,l2=s<bQ2,l3=s<bQ3;
      bQ3 = l3 ? (l2?bQ2:s) : bQ3;
      bQ2 = l2 ? (l1?bQ1:s) : bQ2;
      bQ1 = l1 ? (l0?bQ0:s) : bQ1;
      bQ0 = l0 ? s : bQ0;
    }
  }
  // exact 4th-smallest of union of two sorted quads (bitonic lower-half merge)
  float l0=fminf(bP0,bQ3), l1=fminf(bP1,bQ2), l2=fminf(bP2,bQ1), l3=fminf(bP3,bQ0);
  float b3 = fmaxf(fmaxf(l0,l1), fmaxf(l2,l3));

  // seg <=> 2nd-smallest fg sqrt-dist <= 4th-smallest bg sqrt-dist (fg wins ties)
  bool seg = sqrtf(a1) <= sqrtf(b3);
  __syncthreads();                       // pix reuse fence
  pix[tid*3+0]=seg?ip0:0.f;
  pix[tid*3+1]=seg?ip1:0.f;
  pix[tid*3+2]=seg?ip2:0.f;
  __syncthreads();
  float4* ob4 = (float4*)(out + ((size_t)img*NPIX + (size_t)chunk*256)*3);
  if(tid<192) ob4[tid] = ((float4*)pix)[tid];
}

extern "C" void kernel_launch(void* const* d_in, const int* in_sizes, int n_in,
                              void* d_out, int out_size, void* d_ws, size_t ws_size,
                              hipStream_t stream) {
  const float* in = (const float*)d_in[0];
  float* out = (float*)d_out;
  float* maxpart = (float*)d_ws;                                          // 2304 B
  unsigned long long* key50g = (unsigned long long*)((char*)d_ws + 2304); // 204800 B
  float* ts2g    = (float*)((char*)d_ws + 207104);                        // 76800 B
  float* meanstd = (float*)((char*)d_ws + 283904);                        // 1280 B

  kmax  <<<192,  256, 0, stream>>>(in, maxpart);
  kscore<<<512,  256, 0, stream>>>(in, maxpart, key50g);
  kmerge<<<32,   256, 0, stream>>>(in, key50g, ts2g, meanstd);
  kknn  <<<1152, 256, 0, stream>>>(in, ts2g, meanstd, out);
}